// Round 8
// baseline (983.186 us; speedup 1.0000x reference)
//
#include <hip/hip_runtime.h>
#include <hip/hip_bf16.h>
#include <math.h>

#define WINS 16
#define LTOK 256      // window length L = 16*16
#define CCH  512
#define NH   16
#define DH   32
#define NBW  256
#define LOG_MAX_F 4.605170185988092f
#define EPS_F 1e-12f
#define L2E_F 1.4426950408889634f

typedef __attribute__((ext_vector_type(8))) short bf16x8;   // MFMA A/B frag (4 VGPR)
typedef __attribute__((ext_vector_type(4))) float f32x4;    // MFMA C/D frag

// round-to-nearest-even fp32 -> bf16 (bits)
__device__ __forceinline__ unsigned short bf16rne(float f) {
  unsigned int u = __float_as_uint(f);
  u += 0x7fffu + ((u >> 16) & 1u);
  return (unsigned short)(u >> 16);
}
__device__ __forceinline__ float bf2f(unsigned short s) {
  return __uint_as_float(((unsigned int)s) << 16);
}

// ---------------------------------------------------------------------------
// Kernel 0: split fp32 (rows x 512) into bf16 [hi | lo] (rows x 1024).
// ---------------------------------------------------------------------------
__global__ __launch_bounds__(256) void split_kernel(
    const float* __restrict__ in, unsigned short* __restrict__ out, long nElem)
{
  long total4 = nElem >> 2;
  for (long i4 = (long)blockIdx.x * 256 + threadIdx.x; i4 < total4;
       i4 += (long)gridDim.x * 256) {
    long row = i4 >> 7;              // / (512/4)
    int  kq  = ((int)i4 & 127) << 2;
    float4 a = *(const float4*)&in[(row << 9) + kq];
    unsigned int b0 = __float_as_uint(a.x), b1 = __float_as_uint(a.y);
    unsigned int b2 = __float_as_uint(a.z), b3 = __float_as_uint(a.w);
    ushort4 hi = make_ushort4((unsigned short)(b0 >> 16), (unsigned short)(b1 >> 16),
                              (unsigned short)(b2 >> 16), (unsigned short)(b3 >> 16));
    float l0 = a.x - __uint_as_float(b0 & 0xffff0000u);
    float l1 = a.y - __uint_as_float(b1 & 0xffff0000u);
    float l2 = a.z - __uint_as_float(b2 & 0xffff0000u);
    float l3 = a.w - __uint_as_float(b3 & 0xffff0000u);
    ushort4 lo = make_ushort4(bf16rne(l0), bf16rne(l1), bf16rne(l2), bf16rne(l3));
    *(ushort4*)&out[row * 1024 + kq]       = hi;
    *(ushort4*)&out[row * 1024 + 512 + kq] = lo;
  }
}

// ---------------------------------------------------------------------------
// Kernel 1: relative-position-bias MLP table, layout (H=16, 961).
// ---------------------------------------------------------------------------
__global__ __launch_bounds__(64) void bias_mlp_kernel(
    const float* __restrict__ fc1_w, const float* __restrict__ fc1_b,
    const float* __restrict__ fc2_w, const float* __restrict__ fc2_b,
    float* __restrict__ table)   // (16, 961)
{
  const int e  = blockIdx.x;          // 0..960
  const int di = e / 31 - 15;
  const int dj = e % 31 - 15;
  const float rx = (di > 0 ? 1.f : (di < 0 ? -1.f : 0.f)) * log1pf(fabsf((float)di));
  const float ry = (dj > 0 ? 1.f : (dj < 0 ? -1.f : 0.f)) * log1pf(fabsf((float)dj));
  const int lane = threadIdx.x;       // 0..63

  float acc[NH];
#pragma unroll
  for (int h = 0; h < NH; ++h) acc[h] = 0.f;

  for (int j = lane; j < 512; j += 64) {
    float hid = fmaf(fc1_w[2*j], rx, fmaf(fc1_w[2*j+1], ry, fc1_b[j]));
    hid = fmaxf(hid, 0.f);
#pragma unroll
    for (int h = 0; h < NH; ++h) acc[h] = fmaf(fc2_w[h*512 + j], hid, acc[h]);
  }
#pragma unroll
  for (int h = 0; h < NH; ++h) {
    float v = acc[h];
    for (int off = 32; off > 0; off >>= 1) v += __shfl_down(v, off);
    if (lane == 0) table[h*961 + e] = v + fc2_b[h];
  }
}

// ---------------------------------------------------------------------------
// Kernel 1b: per-head softmax upper bound M_h = scale_h + max_e bias_h[e] + eps.
// ---------------------------------------------------------------------------
__global__ __launch_bounds__(256) void mh_kernel(
    const float* __restrict__ table, const float* __restrict__ lscale,
    float* __restrict__ Mh)
{
  const int t = threadIdx.x, h = t >> 4, l16 = t & 15;
  float bm = -1e30f;
  for (int e = l16; e < 961; e += 16) bm = fmaxf(bm, table[h*961 + e]);
#pragma unroll
  for (int off = 1; off < 16; off <<= 1) bm = fmaxf(bm, __shfl_xor(bm, off));
  if (l16 == 0)
    Mh[h] = __expf(fminf(lscale[h], LOG_MAX_F)) + bm + 1e-3f;
}

// ---------------------------------------------------------------------------
// Kernel 2/4: bf16-split MFMA GEMM, single K-sweep (verified round 7).
// ---------------------------------------------------------------------------
__global__ __launch_bounds__(256) void gemm_mfma_split(
    const unsigned short* __restrict__ A,  // (M, 2K) bf16 [hi|lo]
    const unsigned short* __restrict__ B,  // (N, 2K) bf16 [hi|lo]
    const float* __restrict__ bias,        // (N,)
    float* __restrict__ C,                 // (M, N) fp32
    int M, int N, int K)                   // K = original K (512)
{
  __shared__ unsigned short Ah[128 * 32];  // 8 KB each, 32 KB total
  __shared__ unsigned short Al[128 * 32];
  __shared__ unsigned short Bh[128 * 32];
  __shared__ unsigned short Bl[128 * 32];

  const int nwg  = gridDim.x;
  const int id   = (blockIdx.x & 7) * (nwg >> 3) + (blockIdx.x >> 3);
  const int ntls = N >> 7;
  const int mt = id / ntls, nt = id % ntls;

  const int tid  = threadIdx.x;
  const int wave = tid >> 6;
  const int lane = tid & 63;
  const int wr = wave >> 1, wc = wave & 1;
  const size_t m0 = (size_t)mt * 128, n0 = (size_t)nt * 128;
  const int K2 = 2 * K;

  f32x4 acc[4][4];
#pragma unroll
  for (int i = 0; i < 4; ++i)
#pragma unroll
    for (int j = 0; j < 4; ++j) acc[i][j] = 0.f;

  const int srow = (lane >> 2);       // 0..15
  const int sko  = (lane & 3) * 8;    // bf16 elements (16B chunks)

  for (int kt = 0; kt < K; kt += 32) {
    __syncthreads();                  // prev step's readers done
#pragma unroll
    for (int L = 0; L < 2; ++L) {
      const int r0 = wave * 32 + L * 16;
      const size_t arow = (m0 + r0 + srow) * (size_t)K2;
      const size_t brow = (n0 + r0 + srow) * (size_t)K2;
      __builtin_amdgcn_global_load_lds(
          (const __attribute__((address_space(1))) unsigned int*)&A[arow + kt + sko],
          (__attribute__((address_space(3))) unsigned int*)&Ah[r0 * 32], 16, 0, 0);
      __builtin_amdgcn_global_load_lds(
          (const __attribute__((address_space(1))) unsigned int*)&A[arow + K + kt + sko],
          (__attribute__((address_space(3))) unsigned int*)&Al[r0 * 32], 16, 0, 0);
      __builtin_amdgcn_global_load_lds(
          (const __attribute__((address_space(1))) unsigned int*)&B[brow + kt + sko],
          (__attribute__((address_space(3))) unsigned int*)&Bh[r0 * 32], 16, 0, 0);
      __builtin_amdgcn_global_load_lds(
          (const __attribute__((address_space(1))) unsigned int*)&B[brow + K + kt + sko],
          (__attribute__((address_space(3))) unsigned int*)&Bl[r0 * 32], 16, 0, 0);
    }
    asm volatile("s_waitcnt vmcnt(0)" ::: "memory");
    __syncthreads();                  // all staging landed

    const int fr = lane & 15, fk = (lane >> 4) * 8;
    bf16x8 ah[4], al[4], bh[4], bl[4];
#pragma unroll
    for (int i = 0; i < 4; ++i) {
      const int ra = (wr * 64 + i * 16 + fr) * 32 + fk;
      ah[i] = *(const bf16x8*)&Ah[ra];
      al[i] = *(const bf16x8*)&Al[ra];
    }
#pragma unroll
    for (int j = 0; j < 4; ++j) {
      const int rb = (wc * 64 + j * 16 + fr) * 32 + fk;
      bh[j] = *(const bf16x8*)&Bh[rb];
      bl[j] = *(const bf16x8*)&Bl[rb];
    }
    // 48 MFMA between barrier pairs: hi*hi, hi*lo, lo*hi
#pragma unroll
    for (int i = 0; i < 4; ++i)
#pragma unroll
      for (int j = 0; j < 4; ++j)
        acc[i][j] = __builtin_amdgcn_mfma_f32_16x16x32_bf16(ah[i], bh[j], acc[i][j], 0, 0, 0);
#pragma unroll
    for (int i = 0; i < 4; ++i)
#pragma unroll
      for (int j = 0; j < 4; ++j)
        acc[i][j] = __builtin_amdgcn_mfma_f32_16x16x32_bf16(ah[i], bl[j], acc[i][j], 0, 0, 0);
#pragma unroll
    for (int i = 0; i < 4; ++i)
#pragma unroll
      for (int j = 0; j < 4; ++j)
        acc[i][j] = __builtin_amdgcn_mfma_f32_16x16x32_bf16(al[i], bh[j], acc[i][j], 0, 0, 0);
  }

  const int cr = (lane >> 4) * 4, cc = lane & 15;
#pragma unroll
  for (int j = 0; j < 4; ++j) {
    const size_t col = n0 + wc * 64 + j * 16 + cc;
    const float bv = bias[col];
#pragma unroll
    for (int i = 0; i < 4; ++i) {
      const size_t rbase = m0 + wr * 64 + i * 16 + cr;
#pragma unroll
      for (int r = 0; r < 4; ++r)
        C[(rbase + r) * (size_t)N + col] = acc[i][j][r] + bv;
    }
  }
}

// ---------------------------------------------------------------------------
// Kernel 3: MFMA cosine attention (round-7 verified structure) with:
//  - exp2 folding: log2(e) folded into Q scale and staged bias -> exp2f
//  - lsum via MFMA ones-row (accL) on the idle matrix pipe; epilogue
//    shuffle-free (all D rows of accL equal Sum_k P[k][q], col = ql)
//  - s_setprio(1) around MFMA clusters (T5; independent-wave regime, m191)
// ---------------------------------------------------------------------------
__global__ __launch_bounds__(256) void attn_kernel(
    const float* __restrict__ qkv,      // (CW*256, 1536)
    const float* __restrict__ table,    // (16, 961) fp32
    const float* __restrict__ lscale,   // (16,)
    const float* __restrict__ Mh,       // (16,)
    unsigned short* __restrict__ Osp)   // (CW*256, 1024) bf16 [hi|lo]
{
  __shared__ unsigned short Khi[256 * 40];   // 20 KB
  __shared__ unsigned short Klo[256 * 40];   // 20 KB
  __shared__ unsigned short Vth[32 * 264];   // 16.5 KB
  __shared__ unsigned short Pql[4 * 512];    // 4 KB (1 KB per wave, wave-private)
  __shared__ unsigned short btb[968];        // 1.9 KB: bias*log2e (bf16)

  const int b = blockIdx.x, h = blockIdx.y, t = threadIdx.x;
  const int lane = t & 63, w = t >> 6;
  const int G = lane >> 4, ql = lane & 15;
  const float scale = __expf(fminf(lscale[h], LOG_MAX_F));
  const float Mh2 = Mh[h] * L2E_F;           // bound in log2 units

  // ---- stage K row t: L2-normalize, hi/lo split ----
  {
    const size_t rb = ((size_t)(b*LTOK + t)) * (3*CCH) + CCH + h*DH;
    float4 kr[8]; float nk = 0.f;
#pragma unroll
    for (int c = 0; c < 8; ++c) {
      kr[c] = *(const float4*)&qkv[rb + c*4];
      nk += kr[c].x*kr[c].x + kr[c].y*kr[c].y + kr[c].z*kr[c].z + kr[c].w*kr[c].w;
    }
    const float ik = 1.f / fmaxf(sqrtf(nk), EPS_F);
#pragma unroll
    for (int c = 0; c < 4; ++c) {
      float f[8] = {kr[2*c].x*ik, kr[2*c].y*ik, kr[2*c].z*ik, kr[2*c].w*ik,
                    kr[2*c+1].x*ik, kr[2*c+1].y*ik, kr[2*c+1].z*ik, kr[2*c+1].w*ik};
      bf16x8 hi, lo;
#pragma unroll
      for (int j = 0; j < 8; ++j) {
        unsigned int u = __float_as_uint(f[j]);
        hi[j] = (short)(u >> 16);
        lo[j] = (short)bf16rne(f[j] - __uint_as_float(u & 0xffff0000u));
      }
      *(bf16x8*)&Khi[t*40 + c*8] = hi;
      *(bf16x8*)&Klo[t*40 + c*8] = lo;
    }
  }
  // ---- stage V row t: bf16-RNE, transposed [d][key] ----
  {
    const size_t rb = ((size_t)(b*LTOK + t)) * (3*CCH) + 2*CCH + h*DH;
#pragma unroll
    for (int c = 0; c < 8; ++c) {
      float4 v = *(const float4*)&qkv[rb + c*4];
      Vth[(4*c+0)*264 + t] = bf16rne(v.x);
      Vth[(4*c+1)*264 + t] = bf16rne(v.y);
      Vth[(4*c+2)*264 + t] = bf16rne(v.z);
      Vth[(4*c+3)*264 + t] = bf16rne(v.w);
    }
  }
  // ---- stage bias * log2e (bf16) ----
  for (int e = t; e < 961; e += 256) btb[e] = bf16rne(table[h*961 + e] * L2E_F);

  // ---- Q fragments in registers: [qt] hi/lo, scale*log2e & 1/norm folded ----
  bf16x8 Qh[4], Qlr[4];
#pragma unroll
  for (int qt = 0; qt < 4; ++qt) {
    const int qrow = b*LTOK + w*64 + qt*16 + ql;
    const float* qp = &qkv[(size_t)qrow * (3*CCH) + h*DH + G*8];
    float4 a = *(const float4*)qp;
    float4 b4 = *(const float4*)(qp + 4);
    float ss = a.x*a.x + a.y*a.y + a.z*a.z + a.w*a.w
             + b4.x*b4.x + b4.y*b4.y + b4.z*b4.z + b4.w*b4.w;
    ss += __shfl_xor(ss, 16);
    ss += __shfl_xor(ss, 32);
    const float iq = (scale * L2E_F) / fmaxf(sqrtf(ss), EPS_F);
    float f[8] = {a.x*iq, a.y*iq, a.z*iq, a.w*iq, b4.x*iq, b4.y*iq, b4.z*iq, b4.w*iq};
#pragma unroll
    for (int j = 0; j < 8; ++j) {
      unsigned int u = __float_as_uint(f[j]);
      Qh[qt][j]  = (short)(u >> 16);
      Qlr[qt][j] = (short)bf16rne(f[j] - __uint_as_float(u & 0xffff0000u));
    }
  }
  __syncthreads();

  bf16x8 onesf;
#pragma unroll
  for (int j = 0; j < 8; ++j) onesf[j] = (short)0x3F80;   // bf16 1.0

  f32x4 accO[2][4], accL[4];
#pragma unroll
  for (int j = 0; j < 4; ++j) { accO[0][j] = 0.f; accO[1][j] = 0.f; accL[j] = 0.f; }

  const int pbase = w * 512;   // wave-private P region (ushort units)

  for (int kp = 0; kp < 8; ++kp) {
    bf16x8 kh[2], kl[2], vf[2];
#pragma unroll
    for (int tt = 0; tt < 2; ++tt) {
      const int krow = kp*32 + tt*16 + ql;
      kh[tt] = *(const bf16x8*)&Khi[krow*40 + G*8];
      kl[tt] = *(const bf16x8*)&Klo[krow*40 + G*8];
    }
#pragma unroll
    for (int dt = 0; dt < 2; ++dt)
      vf[dt] = *(const bf16x8*)&Vth[(dt*16 + ql)*264 + kp*32 + G*8];

#pragma unroll
    for (int qt = 0; qt < 4; ++qt) {
      // --- S^T tiles (log2 units): 3-product split, D[key_in_tile, q] ---
      f32x4 st0, st1; st0 = 0.f; st1 = 0.f;
      __builtin_amdgcn_s_setprio(1);
      st0 = __builtin_amdgcn_mfma_f32_16x16x32_bf16(kl[0], Qh[qt],  st0, 0,0,0);
      st0 = __builtin_amdgcn_mfma_f32_16x16x32_bf16(kh[0], Qlr[qt], st0, 0,0,0);
      st0 = __builtin_amdgcn_mfma_f32_16x16x32_bf16(kh[0], Qh[qt],  st0, 0,0,0);
      st1 = __builtin_amdgcn_mfma_f32_16x16x32_bf16(kl[1], Qh[qt],  st1, 0,0,0);
      st1 = __builtin_amdgcn_mfma_f32_16x16x32_bf16(kh[1], Qlr[qt], st1, 0,0,0);
      st1 = __builtin_amdgcn_mfma_f32_16x16x32_bf16(kh[1], Qh[qt],  st1, 0,0,0);
      __builtin_amdgcn_s_setprio(0);

      // --- bias + bound-softmax (exp2) + bf16 pack ---
      const int qg = w*64 + qt*16 + ql;
      const int qi = qg >> 4, qj = qg & 15;
      unsigned short ph[2][4];
#pragma unroll
      for (int tt = 0; tt < 2; ++tt) {
        const int ki = kp*2 + tt;
        const int ib = (qi - ki + 15)*31 + (qj + 15 - 4*G);
#pragma unroll
        for (int r = 0; r < 4; ++r) {
          const float bv = bf2f(btb[ib - r]);
          const float sv = (tt == 0) ? st0[r] : st1[r];
          const float p = exp2f(sv + bv - Mh2);
          ph[tt][r] = bf16rne(p);
        }
      }

      // wave-private LDS bounce; compiler inserts counted lgkmcnt
#pragma unroll
      for (int tt = 0; tt < 2; ++tt) {
        const int chunkw = 2*tt + (G >> 1);
        const int widx = pbase + ql*32 + ((chunkw ^ (ql & 3)) * 8) + (G & 1)*4;
        *(ushort4*)&Pql[widx] = make_ushort4(ph[tt][0], ph[tt][1], ph[tt][2], ph[tt][3]);
      }
      const bf16x8 pb = *(const bf16x8*)&Pql[pbase + ql*32 + ((G ^ (ql & 3)) * 8)];
      __builtin_amdgcn_s_setprio(1);
      accO[0][qt] = __builtin_amdgcn_mfma_f32_16x16x32_bf16(vf[0], pb, accO[0][qt], 0,0,0);
      accO[1][qt] = __builtin_amdgcn_mfma_f32_16x16x32_bf16(vf[1], pb, accO[1][qt], 0,0,0);
      accL[qt]    = __builtin_amdgcn_mfma_f32_16x16x32_bf16(onesf, pb, accL[qt],    0,0,0);
      __builtin_amdgcn_s_setprio(0);
    }
  }

  // ---- epilogue: 1/l (shuffle-free: accL rows all equal Sum_k P), split-write O ----
#pragma unroll
  for (int qt = 0; qt < 4; ++qt) {
    const float inv = 1.f / fmaxf(accL[qt][0], 1e-37f);
    const int qrow = b*LTOK + w*64 + qt*16 + ql;
#pragma unroll
    for (int dt = 0; dt < 2; ++dt) {
      unsigned short hv[4], lv[4];
#pragma unroll
      for (int r = 0; r < 4; ++r) {
        const float v = accO[dt][qt][r] * inv;
        const unsigned int u = __float_as_uint(v);
        hv[r] = (unsigned short)(u >> 16);
        lv[r] = bf16rne(v - __uint_as_float(u & 0xffff0000u));
      }
      unsigned short* ob = &Osp[(size_t)qrow * 1024 + h*DH + dt*16 + G*4];
      *(ushort4*)ob         = make_ushort4(hv[0], hv[1], hv[2], hv[3]);
      *(ushort4*)(ob + 512) = make_ushort4(lv[0], lv[1], lv[2], lv[3]);
    }
  }
}

// ---------------------------------------------------------------------------
// Driver (unchanged from round 7).
// ---------------------------------------------------------------------------
extern "C" void kernel_launch(void* const* d_in, const int* in_sizes, int n_in,
                              void* d_out, int out_size, void* d_ws, size_t ws_size,
                              hipStream_t stream) {
  const float* x      = (const float*)d_in[0];
  const float* qkv_w  = (const float*)d_in[1];
  const float* qkv_b  = (const float*)d_in[2];
  const float* proj_w = (const float*)d_in[3];
  const float* proj_b = (const float*)d_in[4];
  const float* fc1_w  = (const float*)d_in[5];
  const float* fc1_b  = (const float*)d_in[6];
  const float* fc2_w  = (const float*)d_in[7];
  const float* fc2_b  = (const float*)d_in[8];
  const float* ls     = (const float*)d_in[9];
  float* out = (float*)d_out;

  const size_t FIXED   = 65536 + (size_t)1536*1024*2 + (size_t)512*1024*2;
  const size_t PER_WIN = (size_t)LTOK*(3*CCH)*4 + 2*(size_t)LTOK*1024*2; // 2.5 MiB

  int CW = NBW;
  while (CW > 4 && FIXED + (size_t)CW * PER_WIN > ws_size) CW >>= 1;

  char* p = (char*)d_ws;
  float*          table   = (float*)p;          p += 65536;
  unsigned short* qkvw_s  = (unsigned short*)p; p += (size_t)1536*1024*2;
  unsigned short* projw_s = (unsigned short*)p; p += (size_t)512*1024*2;
  float*          qkvbuf  = (float*)p;          p += (size_t)CW*LTOK*(3*CCH)*4;
  unsigned short* xsplit  = (unsigned short*)p; p += (size_t)CW*LTOK*1024*2;
  unsigned short* osplit  = (unsigned short*)p;
  float*          MhPtr   = table + NH*961;     // inside the 64KB table region

  // bias table + M_h + weight splits (once per call)
  bias_mlp_kernel<<<dim3(961), dim3(64), 0, stream>>>(fc1_w, fc1_b, fc2_w, fc2_b, table);
  mh_kernel<<<dim3(1), dim3(256), 0, stream>>>(table, ls, MhPtr);
  split_kernel<<<dim3(768), dim3(256), 0, stream>>>(qkv_w, qkvw_s, (long)1536*512);
  split_kernel<<<dim3(256), dim3(256), 0, stream>>>(proj_w, projw_s, (long)512*512);

  const int Mc = CW * LTOK;
  const long xElems = (long)Mc * CCH;
  const int splitGrid = (int)((xElems/4 + 255) / 256) > 2048 ? 2048
                        : (int)((xElems/4 + 255) / 256);

  for (int c0 = 0; c0 < NBW; c0 += CW) {
    const float* xc = x   + (size_t)c0 * LTOK * CCH;
    float*       oc = out + (size_t)c0 * LTOK * CCH;

    // split x chunk -> [hi|lo] bf16
    split_kernel<<<dim3(splitGrid), dim3(256), 0, stream>>>(xc, xsplit, xElems);

    // QKV projection: (Mc,512) @ (1536,512)^T + bias, split-bf16 MFMA
    gemm_mfma_split<<<dim3((Mc/128) * (1536/128)), dim3(256), 0, stream>>>(
        xsplit, qkvw_s, qkv_b, qkvbuf, Mc, 1536, CCH);

    // MFMA attention per (window-in-chunk, head); writes O in split form
    attn_kernel<<<dim3(CW, NH), dim3(256), 0, stream>>>(
        qkvbuf, table, ls, MhPtr, osplit);

    // output projection: (Mc,512) @ (512,512)^T + bias
    gemm_mfma_split<<<dim3((Mc/128) * (512/128)), dim3(256), 0, stream>>>(
        osplit, projw_s, proj_b, oc, Mc, 512, CCH);
  }
}

// Round 9
// 967.558 us; speedup vs baseline: 1.0162x; 1.0162x over previous
//
#include <hip/hip_runtime.h>
#include <hip/hip_bf16.h>
#include <math.h>

#define WINS 16
#define LTOK 256      // window length L = 16*16
#define CCH  512
#define NH   16
#define DH   32
#define NBW  256
#define LOG_MAX_F 4.605170185988092f
#define EPS_F 1e-12f
#define L2E_F 1.4426950408889634f

typedef __attribute__((ext_vector_type(8))) short bf16x8;   // MFMA A/B frag (4 VGPR)
typedef __attribute__((ext_vector_type(4))) float f32x4;    // MFMA C/D frag

// round-to-nearest-even fp32 -> bf16 (bits)
__device__ __forceinline__ unsigned short bf16rne(float f) {
  unsigned int u = __float_as_uint(f);
  u += 0x7fffu + ((u >> 16) & 1u);
  return (unsigned short)(u >> 16);
}
__device__ __forceinline__ float bf2f(unsigned short s) {
  return __uint_as_float(((unsigned int)s) << 16);
}

// ---------------------------------------------------------------------------
// Kernel 0: split fp32 (rows x 512) into bf16 [hi | lo] (rows x 1024).
// ---------------------------------------------------------------------------
__global__ __launch_bounds__(256) void split_kernel(
    const float* __restrict__ in, unsigned short* __restrict__ out, long nElem)
{
  long total4 = nElem >> 2;
  for (long i4 = (long)blockIdx.x * 256 + threadIdx.x; i4 < total4;
       i4 += (long)gridDim.x * 256) {
    long row = i4 >> 7;              // / (512/4)
    int  kq  = ((int)i4 & 127) << 2;
    float4 a = *(const float4*)&in[(row << 9) + kq];
    unsigned int b0 = __float_as_uint(a.x), b1 = __float_as_uint(a.y);
    unsigned int b2 = __float_as_uint(a.z), b3 = __float_as_uint(a.w);
    ushort4 hi = make_ushort4((unsigned short)(b0 >> 16), (unsigned short)(b1 >> 16),
                              (unsigned short)(b2 >> 16), (unsigned short)(b3 >> 16));
    float l0 = a.x - __uint_as_float(b0 & 0xffff0000u);
    float l1 = a.y - __uint_as_float(b1 & 0xffff0000u);
    float l2 = a.z - __uint_as_float(b2 & 0xffff0000u);
    float l3 = a.w - __uint_as_float(b3 & 0xffff0000u);
    ushort4 lo = make_ushort4(bf16rne(l0), bf16rne(l1), bf16rne(l2), bf16rne(l3));
    *(ushort4*)&out[row * 1024 + kq]       = hi;
    *(ushort4*)&out[row * 1024 + 512 + kq] = lo;
  }
}

// ---------------------------------------------------------------------------
// Kernel 1: relative-position-bias MLP table, layout (H=16, 961).
// ---------------------------------------------------------------------------
__global__ __launch_bounds__(64) void bias_mlp_kernel(
    const float* __restrict__ fc1_w, const float* __restrict__ fc1_b,
    const float* __restrict__ fc2_w, const float* __restrict__ fc2_b,
    float* __restrict__ table)   // (16, 961)
{
  const int e  = blockIdx.x;          // 0..960
  const int di = e / 31 - 15;
  const int dj = e % 31 - 15;
  const float rx = (di > 0 ? 1.f : (di < 0 ? -1.f : 0.f)) * log1pf(fabsf((float)di));
  const float ry = (dj > 0 ? 1.f : (dj < 0 ? -1.f : 0.f)) * log1pf(fabsf((float)dj));
  const int lane = threadIdx.x;       // 0..63

  float acc[NH];
#pragma unroll
  for (int h = 0; h < NH; ++h) acc[h] = 0.f;

  for (int j = lane; j < 512; j += 64) {
    float hid = fmaf(fc1_w[2*j], rx, fmaf(fc1_w[2*j+1], ry, fc1_b[j]));
    hid = fmaxf(hid, 0.f);
#pragma unroll
    for (int h = 0; h < NH; ++h) acc[h] = fmaf(fc2_w[h*512 + j], hid, acc[h]);
  }
#pragma unroll
  for (int h = 0; h < NH; ++h) {
    float v = acc[h];
    for (int off = 32; off > 0; off >>= 1) v += __shfl_down(v, off);
    if (lane == 0) table[h*961 + e] = v + fc2_b[h];
  }
}

// ---------------------------------------------------------------------------
// Kernel 1b: per-head softmax upper bound M_h = scale_h + max_e bias_h[e] + eps.
// ---------------------------------------------------------------------------
__global__ __launch_bounds__(256) void mh_kernel(
    const float* __restrict__ table, const float* __restrict__ lscale,
    float* __restrict__ Mh)
{
  const int t = threadIdx.x, h = t >> 4, l16 = t & 15;
  float bm = -1e30f;
  for (int e = l16; e < 961; e += 16) bm = fmaxf(bm, table[h*961 + e]);
#pragma unroll
  for (int off = 1; off < 16; off <<= 1) bm = fmaxf(bm, __shfl_xor(bm, off));
  if (l16 == 0)
    Mh[h] = __expf(fminf(lscale[h], LOG_MAX_F)) + bm + 1e-3f;
}

// ---------------------------------------------------------------------------
// Kernel 2/4: bf16-split MFMA GEMM, single K-sweep (verified round 7).
// PERM=1 (QKV): scatter C cols head-major -> qkvp[(sel*16+h)][m][d]
// so attention reads contiguous per-(window,head) panels. Per-store
// coalescing unchanged (16 lanes x consecutive d = 64B segments).
// PERM=0 (proj): plain row-major C.
// ---------------------------------------------------------------------------
template<int PERM>
__global__ __launch_bounds__(256) void gemm_mfma_split(
    const unsigned short* __restrict__ A,  // (M, 2K) bf16 [hi|lo]
    const unsigned short* __restrict__ B,  // (N, 2K) bf16 [hi|lo]
    const float* __restrict__ bias,        // (N,)
    float* __restrict__ C,                 // PERM=0: (M,N); PERM=1: (N/32, M, 32)
    int M, int N, int K)                   // K = original K (512)
{
  __shared__ unsigned short Ah[128 * 32];  // 8 KB each, 32 KB total
  __shared__ unsigned short Al[128 * 32];
  __shared__ unsigned short Bh[128 * 32];
  __shared__ unsigned short Bl[128 * 32];

  const int nwg  = gridDim.x;
  const int id   = (blockIdx.x & 7) * (nwg >> 3) + (blockIdx.x >> 3);
  const int ntls = N >> 7;
  const int mt = id / ntls, nt = id % ntls;

  const int tid  = threadIdx.x;
  const int wave = tid >> 6;
  const int lane = tid & 63;
  const int wr = wave >> 1, wc = wave & 1;
  const size_t m0 = (size_t)mt * 128, n0 = (size_t)nt * 128;
  const int K2 = 2 * K;

  f32x4 acc[4][4];
#pragma unroll
  for (int i = 0; i < 4; ++i)
#pragma unroll
    for (int j = 0; j < 4; ++j) acc[i][j] = 0.f;

  const int srow = (lane >> 2);       // 0..15
  const int sko  = (lane & 3) * 8;    // bf16 elements (16B chunks)

  for (int kt = 0; kt < K; kt += 32) {
    __syncthreads();                  // prev step's readers done
#pragma unroll
    for (int L = 0; L < 2; ++L) {
      const int r0 = wave * 32 + L * 16;
      const size_t arow = (m0 + r0 + srow) * (size_t)K2;
      const size_t brow = (n0 + r0 + srow) * (size_t)K2;
      __builtin_amdgcn_global_load_lds(
          (const __attribute__((address_space(1))) unsigned int*)&A[arow + kt + sko],
          (__attribute__((address_space(3))) unsigned int*)&Ah[r0 * 32], 16, 0, 0);
      __builtin_amdgcn_global_load_lds(
          (const __attribute__((address_space(1))) unsigned int*)&A[arow + K + kt + sko],
          (__attribute__((address_space(3))) unsigned int*)&Al[r0 * 32], 16, 0, 0);
      __builtin_amdgcn_global_load_lds(
          (const __attribute__((address_space(1))) unsigned int*)&B[brow + kt + sko],
          (__attribute__((address_space(3))) unsigned int*)&Bh[r0 * 32], 16, 0, 0);
      __builtin_amdgcn_global_load_lds(
          (const __attribute__((address_space(1))) unsigned int*)&B[brow + K + kt + sko],
          (__attribute__((address_space(3))) unsigned int*)&Bl[r0 * 32], 16, 0, 0);
    }
    asm volatile("s_waitcnt vmcnt(0)" ::: "memory");
    __syncthreads();                  // all staging landed

    const int fr = lane & 15, fk = (lane >> 4) * 8;
    bf16x8 ah[4], al[4], bh[4], bl[4];
#pragma unroll
    for (int i = 0; i < 4; ++i) {
      const int ra = (wr * 64 + i * 16 + fr) * 32 + fk;
      ah[i] = *(const bf16x8*)&Ah[ra];
      al[i] = *(const bf16x8*)&Al[ra];
    }
#pragma unroll
    for (int j = 0; j < 4; ++j) {
      const int rb = (wc * 64 + j * 16 + fr) * 32 + fk;
      bh[j] = *(const bf16x8*)&Bh[rb];
      bl[j] = *(const bf16x8*)&Bl[rb];
    }
    // 48 MFMA between barrier pairs: hi*hi, hi*lo, lo*hi
#pragma unroll
    for (int i = 0; i < 4; ++i)
#pragma unroll
      for (int j = 0; j < 4; ++j)
        acc[i][j] = __builtin_amdgcn_mfma_f32_16x16x32_bf16(ah[i], bh[j], acc[i][j], 0, 0, 0);
#pragma unroll
    for (int i = 0; i < 4; ++i)
#pragma unroll
      for (int j = 0; j < 4; ++j)
        acc[i][j] = __builtin_amdgcn_mfma_f32_16x16x32_bf16(ah[i], bl[j], acc[i][j], 0, 0, 0);
#pragma unroll
    for (int i = 0; i < 4; ++i)
#pragma unroll
      for (int j = 0; j < 4; ++j)
        acc[i][j] = __builtin_amdgcn_mfma_f32_16x16x32_bf16(al[i], bh[j], acc[i][j], 0, 0, 0);
  }

  const int cr = (lane >> 4) * 4, cc = lane & 15;
#pragma unroll
  for (int j = 0; j < 4; ++j) {
    const size_t col = n0 + wc * 64 + j * 16 + cc;
    const float bv = bias[col];
#pragma unroll
    for (int i = 0; i < 4; ++i) {
      const size_t rbase = m0 + wr * 64 + i * 16 + cr;
#pragma unroll
      for (int r = 0; r < 4; ++r) {
        const float v = acc[i][j][r] + bv;
        if constexpr (PERM) {
          const size_t plane = (col >> 9) * 16 + ((col >> 5) & 15); // sel*16+h
          C[(plane * (size_t)M + rbase + r) * 32 + (col & 31)] = v;
        } else {
          C[(rbase + r) * (size_t)N + col] = v;
        }
      }
    }
  }
}

// ---------------------------------------------------------------------------
// Kernel 3: MFMA cosine attention on head-major qkv panels.
// One block = (window b, head h), 4 waves, 64 q/wave. Staging reads are now
// fully coalesced: K/V/Q panels are contiguous (Mc,32) slices per (sel,head).
// exp2-folded bound-softmax; lsum via ones-MFMA; NO setprio (round-8 null).
// ---------------------------------------------------------------------------
__global__ __launch_bounds__(256) void attn_kernel(
    const float* __restrict__ qkvp,     // (3*16, Mc, 32) head-major
    int Mc,
    const float* __restrict__ table,    // (16, 961) fp32
    const float* __restrict__ lscale,   // (16,)
    const float* __restrict__ Mh,       // (16,)
    unsigned short* __restrict__ Osp)   // (Mc, 1024) bf16 [hi|lo]
{
  __shared__ unsigned short Khi[256 * 40];   // 20 KB
  __shared__ unsigned short Klo[256 * 40];   // 20 KB
  __shared__ unsigned short Vth[32 * 264];   // 16.5 KB
  __shared__ unsigned short Pql[4 * 512];    // 4 KB (1 KB per wave, wave-private)
  __shared__ unsigned short btb[968];        // 1.9 KB: bias*log2e (bf16)

  const int b = blockIdx.x, h = blockIdx.y, t = threadIdx.x;
  const int lane = t & 63, w = t >> 6;
  const int G = lane >> 4, ql = lane & 15;
  const float scale = __expf(fminf(lscale[h], LOG_MAX_F));
  const float Mh2 = Mh[h] * L2E_F;           // bound in log2 units

  const float* __restrict__ qbase = qkvp + ((size_t)( 0 + h) * Mc + b*LTOK) * 32;
  const float* __restrict__ kbase = qkvp + ((size_t)(16 + h) * Mc + b*LTOK) * 32;
  const float* __restrict__ vbase = qkvp + ((size_t)(32 + h) * Mc + b*LTOK) * 32;

  // ---- stage K row t (contiguous 128B per thread): normalize, hi/lo split ----
  {
    const float* kp_ = kbase + t * 32;
    float4 kr[8]; float nk = 0.f;
#pragma unroll
    for (int c = 0; c < 8; ++c) {
      kr[c] = *(const float4*)&kp_[c*4];
      nk += kr[c].x*kr[c].x + kr[c].y*kr[c].y + kr[c].z*kr[c].z + kr[c].w*kr[c].w;
    }
    const float ik = 1.f / fmaxf(sqrtf(nk), EPS_F);
#pragma unroll
    for (int c = 0; c < 4; ++c) {
      float f[8] = {kr[2*c].x*ik, kr[2*c].y*ik, kr[2*c].z*ik, kr[2*c].w*ik,
                    kr[2*c+1].x*ik, kr[2*c+1].y*ik, kr[2*c+1].z*ik, kr[2*c+1].w*ik};
      bf16x8 hi, lo;
#pragma unroll
      for (int j = 0; j < 8; ++j) {
        unsigned int u = __float_as_uint(f[j]);
        hi[j] = (short)(u >> 16);
        lo[j] = (short)bf16rne(f[j] - __uint_as_float(u & 0xffff0000u));
      }
      *(bf16x8*)&Khi[t*40 + c*8] = hi;
      *(bf16x8*)&Klo[t*40 + c*8] = lo;
    }
  }
  // ---- stage V row t (contiguous): bf16-RNE, transposed [d][key] ----
  {
    const float* vp_ = vbase + t * 32;
#pragma unroll
    for (int c = 0; c < 8; ++c) {
      float4 v = *(const float4*)&vp_[c*4];
      Vth[(4*c+0)*264 + t] = bf16rne(v.x);
      Vth[(4*c+1)*264 + t] = bf16rne(v.y);
      Vth[(4*c+2)*264 + t] = bf16rne(v.z);
      Vth[(4*c+3)*264 + t] = bf16rne(v.w);
    }
  }
  // ---- stage bias * log2e (bf16) ----
  for (int e = t; e < 961; e += 256) btb[e] = bf16rne(table[h*961 + e] * L2E_F);

  // ---- Q fragments in registers: [qt] hi/lo, scale*log2e & 1/norm folded ----
  bf16x8 Qh[4], Qlr[4];
#pragma unroll
  for (int qt = 0; qt < 4; ++qt) {
    const int qrow = w*64 + qt*16 + ql;          // local row in window
    const float* qp = qbase + (size_t)qrow * 32 + G*8;
    float4 a = *(const float4*)qp;
    float4 b4 = *(const float4*)(qp + 4);
    float ss = a.x*a.x + a.y*a.y + a.z*a.z + a.w*a.w
             + b4.x*b4.x + b4.y*b4.y + b4.z*b4.z + b4.w*b4.w;
    ss += __shfl_xor(ss, 16);
    ss += __shfl_xor(ss, 32);
    const float iq = (scale * L2E_F) / fmaxf(sqrtf(ss), EPS_F);
    float f[8] = {a.x*iq, a.y*iq, a.z*iq, a.w*iq, b4.x*iq, b4.y*iq, b4.z*iq, b4.w*iq};
#pragma unroll
    for (int j = 0; j < 8; ++j) {
      unsigned int u = __float_as_uint(f[j]);
      Qh[qt][j]  = (short)(u >> 16);
      Qlr[qt][j] = (short)bf16rne(f[j] - __uint_as_float(u & 0xffff0000u));
    }
  }
  __syncthreads();

  bf16x8 onesf;
#pragma unroll
  for (int j = 0; j < 8; ++j) onesf[j] = (short)0x3F80;   // bf16 1.0

  f32x4 accO[2][4], accL[4];
#pragma unroll
  for (int j = 0; j < 4; ++j) { accO[0][j] = 0.f; accO[1][j] = 0.f; accL[j] = 0.f; }

  const int pbase = w * 512;   // wave-private P region (ushort units)

  for (int kp = 0; kp < 8; ++kp) {
    bf16x8 kh[2], kl[2], vf[2];
#pragma unroll
    for (int tt = 0; tt < 2; ++tt) {
      const int krow = kp*32 + tt*16 + ql;
      kh[tt] = *(const bf16x8*)&Khi[krow*40 + G*8];
      kl[tt] = *(const bf16x8*)&Klo[krow*40 + G*8];
    }
#pragma unroll
    for (int dt = 0; dt < 2; ++dt)
      vf[dt] = *(const bf16x8*)&Vth[(dt*16 + ql)*264 + kp*32 + G*8];

#pragma unroll
    for (int qt = 0; qt < 4; ++qt) {
      // --- S^T tiles (log2 units): 3-product split, D[key_in_tile, q] ---
      f32x4 st0, st1; st0 = 0.f; st1 = 0.f;
      st0 = __builtin_amdgcn_mfma_f32_16x16x32_bf16(kl[0], Qh[qt],  st0, 0,0,0);
      st0 = __builtin_amdgcn_mfma_f32_16x16x32_bf16(kh[0], Qlr[qt], st0, 0,0,0);
      st0 = __builtin_amdgcn_mfma_f32_16x16x32_bf16(kh[0], Qh[qt],  st0, 0,0,0);
      st1 = __builtin_amdgcn_mfma_f32_16x16x32_bf16(kl[1], Qh[qt],  st1, 0,0,0);
      st1 = __builtin_amdgcn_mfma_f32_16x16x32_bf16(kh[1], Qlr[qt], st1, 0,0,0);
      st1 = __builtin_amdgcn_mfma_f32_16x16x32_bf16(kh[1], Qh[qt],  st1, 0,0,0);

      // --- bias + bound-softmax (exp2) + bf16 pack ---
      const int qg = w*64 + qt*16 + ql;
      const int qi = qg >> 4, qj = qg & 15;
      unsigned short ph[2][4];
#pragma unroll
      for (int tt = 0; tt < 2; ++tt) {
        const int ki = kp*2 + tt;
        const int ib = (qi - ki + 15)*31 + (qj + 15 - 4*G);
#pragma unroll
        for (int r = 0; r < 4; ++r) {
          const float bv = bf2f(btb[ib - r]);
          const float sv = (tt == 0) ? st0[r] : st1[r];
          const float p = exp2f(sv + bv - Mh2);
          ph[tt][r] = bf16rne(p);
        }
      }

      // wave-private LDS bounce; compiler inserts counted lgkmcnt
#pragma unroll
      for (int tt = 0; tt < 2; ++tt) {
        const int chunkw = 2*tt + (G >> 1);
        const int widx = pbase + ql*32 + ((chunkw ^ (ql & 3)) * 8) + (G & 1)*4;
        *(ushort4*)&Pql[widx] = make_ushort4(ph[tt][0], ph[tt][1], ph[tt][2], ph[tt][3]);
      }
      const bf16x8 pb = *(const bf16x8*)&Pql[pbase + ql*32 + ((G ^ (ql & 3)) * 8)];
      accO[0][qt] = __builtin_amdgcn_mfma_f32_16x16x32_bf16(vf[0], pb, accO[0][qt], 0,0,0);
      accO[1][qt] = __builtin_amdgcn_mfma_f32_16x16x32_bf16(vf[1], pb, accO[1][qt], 0,0,0);
      accL[qt]    = __builtin_amdgcn_mfma_f32_16x16x32_bf16(onesf, pb, accL[qt],    0,0,0);
    }
  }

  // ---- epilogue: 1/l (shuffle-free via accL), split-write O ----
#pragma unroll
  for (int qt = 0; qt < 4; ++qt) {
    const float inv = 1.f / fmaxf(accL[qt][0], 1e-37f);
    const int qrow = b*LTOK + w*64 + qt*16 + ql;
#pragma unroll
    for (int dt = 0; dt < 2; ++dt) {
      unsigned short hv[4], lv[4];
#pragma unroll
      for (int r = 0; r < 4; ++r) {
        const float v = accO[dt][qt][r] * inv;
        const unsigned int u = __float_as_uint(v);
        hv[r] = (unsigned short)(u >> 16);
        lv[r] = bf16rne(v - __uint_as_float(u & 0xffff0000u));
      }
      unsigned short* ob = &Osp[(size_t)qrow * 1024 + h*DH + dt*16 + G*4];
      *(ushort4*)ob         = make_ushort4(hv[0], hv[1], hv[2], hv[3]);
      *(ushort4*)(ob + 512) = make_ushort4(lv[0], lv[1], lv[2], lv[3]);
    }
  }
}

// ---------------------------------------------------------------------------
// Driver: QKV GEMM writes head-major (PERM=1); proj unchanged (PERM=0).
// ---------------------------------------------------------------------------
extern "C" void kernel_launch(void* const* d_in, const int* in_sizes, int n_in,
                              void* d_out, int out_size, void* d_ws, size_t ws_size,
                              hipStream_t stream) {
  const float* x      = (const float*)d_in[0];
  const float* qkv_w  = (const float*)d_in[1];
  const float* qkv_b  = (const float*)d_in[2];
  const float* proj_w = (const float*)d_in[3];
  const float* proj_b = (const float*)d_in[4];
  const float* fc1_w  = (const float*)d_in[5];
  const float* fc1_b  = (const float*)d_in[6];
  const float* fc2_w  = (const float*)d_in[7];
  const float* fc2_b  = (const float*)d_in[8];
  const float* ls     = (const float*)d_in[9];
  float* out = (float*)d_out;

  const size_t FIXED   = 65536 + (size_t)1536*1024*2 + (size_t)512*1024*2;
  const size_t PER_WIN = (size_t)LTOK*(3*CCH)*4 + 2*(size_t)LTOK*1024*2; // 2.5 MiB

  int CW = NBW;
  while (CW > 4 && FIXED + (size_t)CW * PER_WIN > ws_size) CW >>= 1;

  char* p = (char*)d_ws;
  float*          table   = (float*)p;          p += 65536;
  unsigned short* qkvw_s  = (unsigned short*)p; p += (size_t)1536*1024*2;
  unsigned short* projw_s = (unsigned short*)p; p += (size_t)512*1024*2;
  float*          qkvbuf  = (float*)p;          p += (size_t)CW*LTOK*(3*CCH)*4;
  unsigned short* xsplit  = (unsigned short*)p; p += (size_t)CW*LTOK*1024*2;
  unsigned short* osplit  = (unsigned short*)p;
  float*          MhPtr   = table + NH*961;     // inside the 64KB table region

  // bias table + M_h + weight splits (once per call)
  bias_mlp_kernel<<<dim3(961), dim3(64), 0, stream>>>(fc1_w, fc1_b, fc2_w, fc2_b, table);
  mh_kernel<<<dim3(1), dim3(256), 0, stream>>>(table, ls, MhPtr);
  split_kernel<<<dim3(768), dim3(256), 0, stream>>>(qkv_w, qkvw_s, (long)1536*512);
  split_kernel<<<dim3(256), dim3(256), 0, stream>>>(proj_w, projw_s, (long)512*512);

  const int Mc = CW * LTOK;
  const long xElems = (long)Mc * CCH;
  const int splitGrid = (int)((xElems/4 + 255) / 256) > 2048 ? 2048
                        : (int)((xElems/4 + 255) / 256);

  for (int c0 = 0; c0 < NBW; c0 += CW) {
    const float* xc = x   + (size_t)c0 * LTOK * CCH;
    float*       oc = out + (size_t)c0 * LTOK * CCH;

    // split x chunk -> [hi|lo] bf16
    split_kernel<<<dim3(splitGrid), dim3(256), 0, stream>>>(xc, xsplit, xElems);

    // QKV projection -> head-major panels (3*16, Mc, 32)
    gemm_mfma_split<1><<<dim3((Mc/128) * (1536/128)), dim3(256), 0, stream>>>(
        xsplit, qkvw_s, qkv_b, qkvbuf, Mc, 1536, CCH);

    // MFMA attention per (window-in-chunk, head); writes O in split form
    attn_kernel<<<dim3(CW, NH), dim3(256), 0, stream>>>(
        qkvbuf, Mc, table, ls, MhPtr, osplit);

    // output projection: (Mc,512) @ (512,512)^T + bias
    gemm_mfma_split<0><<<dim3((Mc/128) * (512/128)), dim3(256), 0, stream>>>(
        osplit, projw_s, proj_b, oc, Mc, 512, CCH);
  }
}